// Round 1
// baseline (9411.198 us; speedup 1.0000x reference)
//
#include <hip/hip_runtime.h>
#include <hip/hip_bf16.h>

#define T_TOK 8192
#define DIM 1024
#define NE 8
#define HID 4096

// ---------------- ws layout ----------------
// [0,32)        counts      int[8]
// [32,64)       meanacc     float[8]
// [1024, +256K) elist       int[8][8192]
// [+256K,+512K) cw          float[8][8192]
// [1MB, +128MB) hbuf        float[8192][4096]
#define WS_ELIST_OFF   1024
#define WS_CW_OFF      (1024 + NE * T_TOK * 4)
#define WS_HBUF_OFF    (1u << 20)

// =====================================================================
// Gating: logits (fp64 accum), top-2 softmax, full softmax for probs,
// routing lists via atomics, block-reduced mean_probs accumulation.
// One wave per token, 4 waves per block.
// =====================================================================
__global__ __launch_bounds__(256) void gate_kernel(
    const float* __restrict__ x, const float* __restrict__ gw,
    int* __restrict__ counts, float* __restrict__ meanacc,
    int* __restrict__ elist, float* __restrict__ cw)
{
    __shared__ float pshare[4][NE];
    const int wave = threadIdx.x >> 6;
    const int lane = threadIdx.x & 63;
    const int t = blockIdx.x * 4 + wave;

    double acc[NE];
#pragma unroll
    for (int e = 0; e < NE; ++e) acc[e] = 0.0;

    const float* xrow = x + (size_t)t * DIM;
#pragma unroll
    for (int jj = 0; jj < 4; ++jj) {
        const int d0 = jj * 256 + lane * 4;
        const float4 xv = *(const float4*)(xrow + d0);
#pragma unroll
        for (int c = 0; c < 4; ++c) {
            const float xs = (&xv.x)[c];
            const float* g = gw + (size_t)(d0 + c) * NE;
            const float4 g0 = *(const float4*)(g);
            const float4 g1 = *(const float4*)(g + 4);
            acc[0] += (double)xs * (double)g0.x;
            acc[1] += (double)xs * (double)g0.y;
            acc[2] += (double)xs * (double)g0.z;
            acc[3] += (double)xs * (double)g0.w;
            acc[4] += (double)xs * (double)g1.x;
            acc[5] += (double)xs * (double)g1.y;
            acc[6] += (double)xs * (double)g1.z;
            acc[7] += (double)xs * (double)g1.w;
        }
    }
    // 64-lane butterfly reduce each of the 8 accumulators
#pragma unroll
    for (int e = 0; e < NE; ++e) {
#pragma unroll
        for (int off = 32; off > 0; off >>= 1)
            acc[e] += __shfl_xor(acc[e], off, 64);
    }

    if (lane == 0) {
        float lg[NE];
#pragma unroll
        for (int e = 0; e < NE; ++e) lg[e] = (float)acc[e];
        // top-2, earliest index wins ties (matches lax.top_k)
        int i1 = 0;
#pragma unroll
        for (int e = 1; e < NE; ++e) if (lg[e] > lg[i1]) i1 = e;
        int i2 = (i1 == 0) ? 1 : 0;
#pragma unroll
        for (int e = 0; e < NE; ++e) if (e != i1 && lg[e] > lg[i2]) i2 = e;
        // softmax over the two selected logits (lg[i1] >= lg[i2])
        const float e2v = expf(lg[i2] - lg[i1]);
        const float s2 = 1.0f + e2v;
        const float w1 = 1.0f / s2;
        const float w2 = e2v / s2;
        // full softmax for probs
        float m8 = lg[0];
#pragma unroll
        for (int e = 1; e < NE; ++e) m8 = fmaxf(m8, lg[e]);
        float p[NE]; float s8 = 0.0f;
#pragma unroll
        for (int e = 0; e < NE; ++e) { p[e] = expf(lg[e] - m8); s8 += p[e]; }
        const float inv = 1.0f / s8;
#pragma unroll
        for (int e = 0; e < NE; ++e) pshare[wave][e] = p[e] * inv;

        int pos1 = atomicAdd(&counts[i1], 1);
        elist[i1 * T_TOK + pos1] = t;
        cw[i1 * T_TOK + pos1] = w1;
        int pos2 = atomicAdd(&counts[i2], 1);
        elist[i2 * T_TOK + pos2] = t;
        cw[i2 * T_TOK + pos2] = w2;
    }
    __syncthreads();
    if (threadIdx.x < NE) {
        float s = pshare[0][threadIdx.x] + pshare[1][threadIdx.x] +
                  pshare[2][threadIdx.x] + pshare[3][threadIdx.x];
        atomicAdd(&meanacc[threadIdx.x], s);
    }
}

// =====================================================================
// Finalize: mean_probs /= T, lbl = E * sum(mean^2) -> tail of d_out
// =====================================================================
__global__ void finalize_kernel(const float* __restrict__ meanacc,
                                float* __restrict__ out)
{
    __shared__ float sq[NE];
    const int tid = threadIdx.x;
    if (tid < NE) {
        float m = meanacc[tid] * (1.0f / (float)T_TOK);
        out[(size_t)T_TOK * DIM + 1 + tid] = m;
        sq[tid] = m * m;
    }
    __syncthreads();
    if (tid == 0) {
        float s = 0.0f;
#pragma unroll
        for (int e = 0; e < NE; ++e) s += sq[e];
        out[(size_t)T_TOK * DIM] = (float)NE * s;
    }
}

// =====================================================================
// GEMM1 (per expert): H = silu(Xg @ Wg) * (Xg @ Wu),  Xg gathered rows.
// 64x64 tile, BK=16, 256 threads, 4x4 per thread per output matrix.
// A stored transposed in LDS (Ast[k][m]) for b128 fragment reads.
// =====================================================================
__global__ __launch_bounds__(256) void gemm1_kernel(
    const float* __restrict__ x,
    const float* __restrict__ wg_all, const float* __restrict__ wu_all,
    const int* __restrict__ counts, const int* __restrict__ elist,
    float* __restrict__ hbuf, int e)
{
    const int cnt = counts[e];
    const int row0 = blockIdx.x * 64;
    if (row0 >= cnt) return;
    const int col0 = blockIdx.y * 64;

    __shared__ float Ast[16][68];
    __shared__ float Bg[16][64];
    __shared__ float Bu[16][64];
    __shared__ int rows[64];

    const int tid = threadIdx.x;
    if (tid < 64) {
        int pos = row0 + tid;
        rows[tid] = (pos < cnt) ? elist[e * T_TOK + pos] : 0;
    }
    __syncthreads();

    const float* wg = wg_all + (size_t)e * DIM * HID;
    const float* wu = wu_all + (size_t)e * DIM * HID;
    const int tx = tid & 15, ty = tid >> 4;
    const int ar = tid >> 2, ac = (tid & 3) * 4;
    const int br = tid >> 4, bc = (tid & 15) * 4;
    const int myrow = rows[ar];

    float ag[4][4] = {{0.f}}, au[4][4] = {{0.f}};

    for (int k0 = 0; k0 < DIM; k0 += 16) {
        const float4 av = *(const float4*)(x + (size_t)myrow * DIM + k0 + ac);
        const float4 bgv = *(const float4*)(wg + (size_t)(k0 + br) * HID + col0 + bc);
        const float4 buv = *(const float4*)(wu + (size_t)(k0 + br) * HID + col0 + bc);
        Ast[ac + 0][ar] = av.x;
        Ast[ac + 1][ar] = av.y;
        Ast[ac + 2][ar] = av.z;
        Ast[ac + 3][ar] = av.w;
        *(float4*)&Bg[br][bc] = bgv;
        *(float4*)&Bu[br][bc] = buv;
        __syncthreads();
#pragma unroll
        for (int kk = 0; kk < 16; ++kk) {
            const float4 a4 = *(const float4*)&Ast[kk][ty * 4];
            const float4 bg4 = *(const float4*)&Bg[kk][tx * 4];
            const float4 bu4 = *(const float4*)&Bu[kk][tx * 4];
            const float a[4] = {a4.x, a4.y, a4.z, a4.w};
            const float bgj[4] = {bg4.x, bg4.y, bg4.z, bg4.w};
            const float buj[4] = {bu4.x, bu4.y, bu4.z, bu4.w};
#pragma unroll
            for (int i = 0; i < 4; ++i)
#pragma unroll
                for (int j = 0; j < 4; ++j) {
                    ag[i][j] += a[i] * bgj[j];
                    au[i][j] += a[i] * buj[j];
                }
        }
        __syncthreads();
    }

#pragma unroll
    for (int i = 0; i < 4; ++i) {
        const int pos = row0 + ty * 4 + i;
        if (pos < cnt) {
            float4 hv;
#pragma unroll
            for (int j = 0; j < 4; ++j) {
                const float g = ag[i][j];
                const float u = au[i][j];
                const float sil = g / (1.0f + expf(-g));
                (&hv.x)[j] = sil * u;
            }
            *(float4*)(hbuf + (size_t)pos * HID + col0 + tx * 4) = hv;
        }
    }
}

// =====================================================================
// GEMM2 (per expert): Y = H_e @ Wd, out[token] += cw * Y  (scatter, no
// atomics needed: experts serialized as separate launches; token rows
// unique within an expert).
// =====================================================================
__global__ __launch_bounds__(256) void gemm2_kernel(
    const float* __restrict__ hbuf, const float* __restrict__ wd_all,
    const int* __restrict__ counts, const int* __restrict__ elist,
    const float* __restrict__ cw, float* __restrict__ out, int e)
{
    const int cnt = counts[e];
    const int row0 = blockIdx.x * 64;
    if (row0 >= cnt) return;
    const int col0 = blockIdx.y * 64;

    __shared__ float Ast[16][68];
    __shared__ float Bs[16][64];
    __shared__ int rows[64];
    __shared__ float cws[64];

    const int tid = threadIdx.x;
    if (tid < 64) {
        int pos = row0 + tid;
        const bool v = pos < cnt;
        rows[tid] = v ? elist[e * T_TOK + pos] : 0;
        cws[tid] = v ? cw[e * T_TOK + pos] : 0.0f;
    }
    __syncthreads();

    const float* wd = wd_all + (size_t)e * HID * DIM;
    const int tx = tid & 15, ty = tid >> 4;
    const int ar = tid >> 2, ac = (tid & 3) * 4;
    const int br = tid >> 4, bc = (tid & 15) * 4;

    float acc[4][4] = {{0.f}};

    for (int k0 = 0; k0 < HID; k0 += 16) {
        const float4 av = *(const float4*)(hbuf + (size_t)(row0 + ar) * HID + k0 + ac);
        const float4 bv = *(const float4*)(wd + (size_t)(k0 + br) * DIM + col0 + bc);
        Ast[ac + 0][ar] = av.x;
        Ast[ac + 1][ar] = av.y;
        Ast[ac + 2][ar] = av.z;
        Ast[ac + 3][ar] = av.w;
        *(float4*)&Bs[br][bc] = bv;
        __syncthreads();
#pragma unroll
        for (int kk = 0; kk < 16; ++kk) {
            const float4 a4 = *(const float4*)&Ast[kk][ty * 4];
            const float4 b4 = *(const float4*)&Bs[kk][tx * 4];
            const float a[4] = {a4.x, a4.y, a4.z, a4.w};
            const float b[4] = {b4.x, b4.y, b4.z, b4.w};
#pragma unroll
            for (int i = 0; i < 4; ++i)
#pragma unroll
                for (int j = 0; j < 4; ++j)
                    acc[i][j] += a[i] * b[j];
        }
        __syncthreads();
    }

#pragma unroll
    for (int i = 0; i < 4; ++i) {
        const int pos = row0 + ty * 4 + i;
        if (pos < cnt) {
            const int t = rows[ty * 4 + i];
            const float w = cws[ty * 4 + i];
            float* op = out + (size_t)t * DIM + col0 + tx * 4;
            float4 o = *(float4*)op;
            o.x += w * acc[i][0];
            o.y += w * acc[i][1];
            o.z += w * acc[i][2];
            o.w += w * acc[i][3];
            *(float4*)op = o;
        }
    }
}

// =====================================================================
extern "C" void kernel_launch(void* const* d_in, const int* in_sizes, int n_in,
                              void* d_out, int out_size, void* d_ws, size_t ws_size,
                              hipStream_t stream)
{
    const float* x     = (const float*)d_in[0];
    const float* gw    = (const float*)d_in[1];
    const float* wgate = (const float*)d_in[2];
    const float* wup   = (const float*)d_in[3];
    const float* wdown = (const float*)d_in[4];
    float* out = (float*)d_out;

    char* ws = (char*)d_ws;
    int*   counts  = (int*)(ws);
    float* meanacc = (float*)(ws + 32);
    int*   elist   = (int*)(ws + WS_ELIST_OFF);
    float* cw      = (float*)(ws + WS_CW_OFF);
    float* hbuf    = (float*)(ws + WS_HBUF_OFF);

    // zero routing counters + mean-probs accumulator + output (out is RMW'd)
    hipMemsetAsync(ws, 0, 1024, stream);
    hipMemsetAsync(d_out, 0, (size_t)out_size * sizeof(float), stream);

    gate_kernel<<<T_TOK / 4, 256, 0, stream>>>(x, gw, counts, meanacc, elist, cw);
    finalize_kernel<<<1, 64, 0, stream>>>(meanacc, out);

    for (int e = 0; e < NE; ++e) {
        gemm1_kernel<<<dim3(T_TOK / 64, HID / 64), 256, 0, stream>>>(
            x, wgate, wup, counts, elist, hbuf, e);
        gemm2_kernel<<<dim3(T_TOK / 64, DIM / 64), 256, 0, stream>>>(
            hbuf, wdown, counts, elist, cw, out, e);
    }
}

// Round 3
// 1960.244 us; speedup vs baseline: 4.8010x; 4.8010x over previous
//
#include <hip/hip_runtime.h>
#include <hip/hip_bf16.h>

#define T_TOK 8192
#define DIM 1024
#define NE 8
#define HID 4096

typedef unsigned short u16;
typedef unsigned int u32;
typedef __attribute__((ext_vector_type(8))) short bf16x8s;  // 8 bf16 in 4 VGPRs
typedef __attribute__((ext_vector_type(4))) float f32x4;

// ---------------- ws layout ----------------
// common: [0,32) counts  [32,64) meanacc  [1024,+256K) elist  [+256K,+512K) cw
// mfma path:
//   [1MB,+16MB)   x_bf16
//   [17MB,+4*64MB) planes phase1: wg_hi, wg_lo, wu_hi, wu_lo   [E][N][K] swizzled
//                  phase2 (after gemm1, aliased over wg): wd_hi, wd_lo
//   [273MB,+135MB) hbuf bf16 [2*T_TOK+128][HID]
// fp32 fallback: [1MB,+128MB) hbuf fp32
#define WS_ELIST_OFF   1024
#define WS_CW_OFF      (1024 + NE * T_TOK * 4)
#define WS_HBUF_OFF    (1u << 20)

__device__ __forceinline__ u16 f2bf(float f) {
    u32 u = __float_as_uint(f);
    u32 r = (u + 0x7FFFu + ((u >> 16) & 1u)) >> 16;   // RNE
    return (u16)r;
}
__device__ __forceinline__ float bf2f(u16 b) {
    return __uint_as_float(((u32)b) << 16);
}

typedef const __attribute__((address_space(1))) u32* gp1_t;
typedef __attribute__((address_space(3))) u32* lp3_t;
__device__ __forceinline__ void gload16(const void* g, void* l) {
    __builtin_amdgcn_global_load_lds((gp1_t)g, (lp3_t)l, 16, 0, 0);
}

// =====================================================================
// Gating (verified in round 0): fp64 logits, top-2 softmax, routing
// lists, mean_probs accumulation. One wave per token.
// =====================================================================
__global__ __launch_bounds__(256) void gate_kernel(
    const float* __restrict__ x, const float* __restrict__ gw,
    int* __restrict__ counts, float* __restrict__ meanacc,
    int* __restrict__ elist, float* __restrict__ cw)
{
    __shared__ float pshare[4][NE];
    const int wave = threadIdx.x >> 6;
    const int lane = threadIdx.x & 63;
    const int t = blockIdx.x * 4 + wave;

    double acc[NE];
#pragma unroll
    for (int e = 0; e < NE; ++e) acc[e] = 0.0;

    const float* xrow = x + (size_t)t * DIM;
#pragma unroll
    for (int jj = 0; jj < 4; ++jj) {
        const int d0 = jj * 256 + lane * 4;
        const float4 xv = *(const float4*)(xrow + d0);
#pragma unroll
        for (int c = 0; c < 4; ++c) {
            const float xs = (&xv.x)[c];
            const float* g = gw + (size_t)(d0 + c) * NE;
            const float4 g0 = *(const float4*)(g);
            const float4 g1 = *(const float4*)(g + 4);
            acc[0] += (double)xs * (double)g0.x;
            acc[1] += (double)xs * (double)g0.y;
            acc[2] += (double)xs * (double)g0.z;
            acc[3] += (double)xs * (double)g0.w;
            acc[4] += (double)xs * (double)g1.x;
            acc[5] += (double)xs * (double)g1.y;
            acc[6] += (double)xs * (double)g1.z;
            acc[7] += (double)xs * (double)g1.w;
        }
    }
#pragma unroll
    for (int e = 0; e < NE; ++e) {
#pragma unroll
        for (int off = 32; off > 0; off >>= 1)
            acc[e] += __shfl_xor(acc[e], off, 64);
    }

    if (lane == 0) {
        float lg[NE];
#pragma unroll
        for (int e = 0; e < NE; ++e) lg[e] = (float)acc[e];
        int i1 = 0;
#pragma unroll
        for (int e = 1; e < NE; ++e) if (lg[e] > lg[i1]) i1 = e;
        int i2 = (i1 == 0) ? 1 : 0;
#pragma unroll
        for (int e = 0; e < NE; ++e) if (e != i1 && lg[e] > lg[i2]) i2 = e;
        const float e2v = expf(lg[i2] - lg[i1]);
        const float s2 = 1.0f + e2v;
        const float w1 = 1.0f / s2;
        const float w2 = e2v / s2;
        float m8 = lg[0];
#pragma unroll
        for (int e = 1; e < NE; ++e) m8 = fmaxf(m8, lg[e]);
        float p[NE]; float s8 = 0.0f;
#pragma unroll
        for (int e = 0; e < NE; ++e) { p[e] = expf(lg[e] - m8); s8 += p[e]; }
        const float inv = 1.0f / s8;
#pragma unroll
        for (int e = 0; e < NE; ++e) pshare[wave][e] = p[e] * inv;

        int pos1 = atomicAdd(&counts[i1], 1);
        elist[i1 * T_TOK + pos1] = t;
        cw[i1 * T_TOK + pos1] = w1;
        int pos2 = atomicAdd(&counts[i2], 1);
        elist[i2 * T_TOK + pos2] = t;
        cw[i2 * T_TOK + pos2] = w2;
    }
    __syncthreads();
    if (threadIdx.x < NE) {
        float s = pshare[0][threadIdx.x] + pshare[1][threadIdx.x] +
                  pshare[2][threadIdx.x] + pshare[3][threadIdx.x];
        atomicAdd(&meanacc[threadIdx.x], s);
    }
}

__global__ void finalize_kernel(const float* __restrict__ meanacc,
                                float* __restrict__ out)
{
    __shared__ float sq[NE];
    const int tid = threadIdx.x;
    if (tid < NE) {
        float m = meanacc[tid] * (1.0f / (float)T_TOK);
        out[(size_t)T_TOK * DIM + 1 + tid] = m;
        sq[tid] = m * m;
    }
    __syncthreads();
    if (tid == 0) {
        float s = 0.0f;
#pragma unroll
        for (int e = 0; e < NE; ++e) s += sq[e];
        out[(size_t)T_TOK * DIM] = (float)NE * s;
    }
}

// =====================================================================
// Weight conversion: fp32 [E][K][N] -> bf16 hi/lo planes [E][N][K],
// 16B chunks of each aligned 64-elem K-window XOR-swizzled by (n&7):
// slot s of row n's window holds global chunk s ^ (n&7).
// =====================================================================
__global__ __launch_bounds__(256) void convert_wt(
    const float* __restrict__ src, u16* __restrict__ dhi, u16* __restrict__ dlo,
    int K, int N)
{
    const int e = blockIdx.z;
    const int k0 = blockIdx.y * 64;
    const int n0 = blockIdx.x * 64;
    const int wave = threadIdx.x >> 6, lane = threadIdx.x & 63;
    const int n = n0 + lane;
#pragma unroll
    for (int cc = 0; cc < 2; ++cc) {
        const int c = wave + cc * 4;                  // chunk 0..7 (8 bf16 each)
        u32 hi[4], lo[4];
#pragma unroll
        for (int j2 = 0; j2 < 4; ++j2) {
            float f0 = src[((size_t)e * K + k0 + c * 8 + j2 * 2 + 0) * N + n];
            float f1 = src[((size_t)e * K + k0 + c * 8 + j2 * 2 + 1) * N + n];
            u16 h0 = f2bf(f0), h1 = f2bf(f1);
            u16 l0 = f2bf(f0 - bf2f(h0)), l1 = f2bf(f1 - bf2f(h1));
            hi[j2] = (u32)h0 | ((u32)h1 << 16);
            lo[j2] = (u32)l0 | ((u32)l1 << 16);
        }
        const int slot = c ^ (n & 7);
        size_t obase = ((size_t)e * N + n) * K + k0 + (size_t)slot * 8;
        *(uint4*)(dhi + obase) = make_uint4(hi[0], hi[1], hi[2], hi[3]);
        *(uint4*)(dlo + obase) = make_uint4(lo[0], lo[1], lo[2], lo[3]);
    }
}

__global__ __launch_bounds__(256) void convert_x(
    const float* __restrict__ src, u16* __restrict__ dst, int n4)
{
    int i = blockIdx.x * 256 + threadIdx.x;
    if (i >= n4) return;
    float4 v = ((const float4*)src)[i];
    uint2 r;
    r.x = (u32)f2bf(v.x) | ((u32)f2bf(v.y) << 16);
    r.y = (u32)f2bf(v.z) | ((u32)f2bf(v.w) << 16);
    ((uint2*)dst)[i] = r;
}

// =====================================================================
// GEMM1 (all experts, one launch): H = silu(Xg@Wg) * (Xg@Wu)
// 128x64 tile (cols shared g/u), BK=64, 4 waves (2x2), MFMA 16x16x32 bf16.
// Weights hi+lo chained into same fp32 acc. LDS 48 KB, XOR-swizzled.
// =====================================================================
#define G1_BM 128
#define G1_BN 64
#define G1_BK 64

__global__ __launch_bounds__(256, 2) void gemm1_mfma(
    const u16* __restrict__ xb,
    const u16* __restrict__ wghi, const u16* __restrict__ wglo,
    const u16* __restrict__ wuhi, const u16* __restrict__ wulo,
    const int* __restrict__ counts, const int* __restrict__ elist,
    u16* __restrict__ hbuf)
{
    const int e = blockIdx.z;
    const int cnt = counts[e];
    const int row0 = blockIdx.x * G1_BM;
    if (row0 >= cnt) return;
    const int n0 = blockIdx.y * G1_BN;
    int hbase = 0;
    for (int i = 0; i < e; ++i) hbase += counts[i];

    __shared__ u16 As[G1_BM * G1_BK];       // 16 KB: [m][8 slots x 16B]
    __shared__ u16 Bs[4][G1_BN * G1_BK];    // 4 x 8 KB: ghi,glo,uhi,ulo

    const int tid = threadIdx.x;
    const int wave = tid >> 6, lane = tid & 63;
    const int wm = wave >> 1, wn = wave & 1;

    // gathered token rows this wave stages (rows wave*32 .. +31)
    int tok[4];
#pragma unroll
    for (int i = 0; i < 4; ++i) {
        int m = wave * 32 + i * 8 + (lane >> 3);
        int pos = row0 + m;
        tok[i] = (pos < cnt) ? elist[e * T_TOK + pos] : 0;
    }
    const u16* bplane = (wave == 0) ? wghi : (wave == 1) ? wglo
                       : (wave == 2) ? wuhi : wulo;

    f32x4 accG[4][2], accU[4][2];
#pragma unroll
    for (int i = 0; i < 4; ++i)
#pragma unroll
        for (int j = 0; j < 2; ++j) {
            accG[i][j] = (f32x4){0.f, 0.f, 0.f, 0.f};
            accU[i][j] = (f32x4){0.f, 0.f, 0.f, 0.f};
        }

    for (int k0 = 0; k0 < DIM; k0 += G1_BK) {
        // ---- stage (global_load_lds 16B/lane, linear LDS dest;
        //       swizzle realized by inverse-permuting the SOURCE chunk) ----
        const int srcchunk = (lane & 7) ^ ((lane >> 3) & 7);
#pragma unroll
        for (int i = 0; i < 4; ++i) {
            const void* src = (const char*)xb + ((size_t)tok[i] * DIM + k0) * 2 + srcchunk * 16;
            void* dst = (char*)As + (wave * 32 + i * 8) * 128 + lane * 16;
            gload16(src, dst);
        }
#pragma unroll
        for (int j = 0; j < 8; ++j) {               // plane storage pre-swizzled
            int n = n0 + j * 8 + (lane >> 3);
            const void* src = (const char*)bplane + ((size_t)(e * HID + n) * DIM + k0) * 2 + (lane & 7) * 16;
            void* dst = (char*)Bs[wave] + (j * 8) * 128 + lane * 16;
            gload16(src, dst);
        }
        __syncthreads();
        // ---- compute ----
#pragma unroll
        for (int kf = 0; kf < 2; ++kf) {
            bf16x8s a[4];
#pragma unroll
            for (int mf = 0; mf < 4; ++mf) {
                int m = wm * 64 + mf * 16 + (lane & 15);
                int slot = (kf * 4 + (lane >> 4)) ^ (m & 7);
                a[mf] = *(const bf16x8s*)((const char*)As + m * 128 + slot * 16);
            }
#pragma unroll
            for (int nf = 0; nf < 2; ++nf) {
                int n = wn * 32 + nf * 16 + (lane & 15);
                int slot = (kf * 4 + (lane >> 4)) ^ (n & 7);
                bf16x8s bgh = *(const bf16x8s*)((const char*)Bs[0] + n * 128 + slot * 16);
                bf16x8s bgl = *(const bf16x8s*)((const char*)Bs[1] + n * 128 + slot * 16);
                bf16x8s buh = *(const bf16x8s*)((const char*)Bs[2] + n * 128 + slot * 16);
                bf16x8s bul = *(const bf16x8s*)((const char*)Bs[3] + n * 128 + slot * 16);
#pragma unroll
                for (int mf = 0; mf < 4; ++mf) {
                    accG[mf][nf] = __builtin_amdgcn_mfma_f32_16x16x32_bf16(a[mf], bgh, accG[mf][nf], 0, 0, 0);
                    accG[mf][nf] = __builtin_amdgcn_mfma_f32_16x16x32_bf16(a[mf], bgl, accG[mf][nf], 0, 0, 0);
                    accU[mf][nf] = __builtin_amdgcn_mfma_f32_16x16x32_bf16(a[mf], buh, accU[mf][nf], 0, 0, 0);
                    accU[mf][nf] = __builtin_amdgcn_mfma_f32_16x16x32_bf16(a[mf], bul, accU[mf][nf], 0, 0, 0);
                }
            }
        }
        __syncthreads();
    }
    // epilogue: h = silu(g)*u -> bf16 hbuf (C layout: col=lane&15, row=(lane>>4)*4+r)
#pragma unroll
    for (int mf = 0; mf < 4; ++mf) {
#pragma unroll
        for (int nf = 0; nf < 2; ++nf) {
            int col = n0 + wn * 32 + nf * 16 + (lane & 15);
#pragma unroll
            for (int r = 0; r < 4; ++r) {
                int pos = row0 + wm * 64 + mf * 16 + (lane >> 4) * 4 + r;
                if (pos < cnt) {
                    float g = accG[mf][nf][r];
                    float u = accU[mf][nf][r];
                    float h = (g / (1.0f + expf(-g))) * u;
                    hbuf[(size_t)(hbase + pos) * HID + col] = f2bf(h);
                }
            }
        }
    }
}

// =====================================================================
// GEMM2 (all experts, one launch): out[tok] += cw * (H_e @ Wd)
// 128x128 tile, BK=64, atomicAdd scatter (2 writers per token row).
// =====================================================================
#define G2_BM 128
#define G2_BN 128
#define G2_BK 64

__global__ __launch_bounds__(256, 2) void gemm2_mfma(
    const u16* __restrict__ hbuf,
    const u16* __restrict__ wdhi, const u16* __restrict__ wdlo,
    const int* __restrict__ counts, const int* __restrict__ elist,
    const float* __restrict__ cw, float* __restrict__ out)
{
    const int e = blockIdx.z;
    const int cnt = counts[e];
    const int row0 = blockIdx.x * G2_BM;
    if (row0 >= cnt) return;
    const int n0 = blockIdx.y * G2_BN;
    int hbase = 0;
    for (int i = 0; i < e; ++i) hbase += counts[i];

    __shared__ u16 As[G2_BM * G2_BK];       // 16 KB
    __shared__ u16 Bs[2][G2_BN * G2_BK];    // 2 x 16 KB (hi, lo)
    __shared__ int toks[G2_BM];
    __shared__ float cws[G2_BM];

    const int tid = threadIdx.x;
    const int wave = tid >> 6, lane = tid & 63;
    const int wm = wave >> 1, wn = wave & 1;

    if (tid < G2_BM) {
        int pos = row0 + tid;
        bool v = pos < cnt;
        toks[tid] = v ? elist[e * T_TOK + pos] : 0;
        cws[tid]  = v ? cw[e * T_TOK + pos] : 0.0f;
    }

    f32x4 acc[4][4];
#pragma unroll
    for (int i = 0; i < 4; ++i)
#pragma unroll
        for (int j = 0; j < 4; ++j) acc[i][j] = (f32x4){0.f, 0.f, 0.f, 0.f};

    const u16* bpl = (wave < 2) ? wdhi : wdlo;

    for (int k0 = 0; k0 < HID; k0 += G2_BK) {
        const int srcchunk = (lane & 7) ^ ((lane >> 3) & 7);
#pragma unroll
        for (int i = 0; i < 4; ++i) {
            const void* src = (const char*)hbuf + ((size_t)(hbase + row0 + wave * 32 + i * 8 + (lane >> 3)) * HID + k0) * 2 + srcchunk * 16;
            void* dst = (char*)As + (wave * 32 + i * 8) * 128 + lane * 16;
            gload16(src, dst);
        }
#pragma unroll
        for (int j = 0; j < 8; ++j) {
            int n = n0 + (wave & 1) * 64 + j * 8 + (lane >> 3);
            const void* src = (const char*)bpl + ((size_t)(e * DIM + n) * HID + k0) * 2 + (lane & 7) * 16;
            void* dst = (char*)Bs[wave >> 1] + ((wave & 1) * 64 + j * 8) * 128 + lane * 16;
            gload16(src, dst);
        }
        __syncthreads();
#pragma unroll
        for (int kf = 0; kf < 2; ++kf) {
            bf16x8s a[4];
#pragma unroll
            for (int mf = 0; mf < 4; ++mf) {
                int m = wm * 64 + mf * 16 + (lane & 15);
                int slot = (kf * 4 + (lane >> 4)) ^ (m & 7);
                a[mf] = *(const bf16x8s*)((const char*)As + m * 128 + slot * 16);
            }
#pragma unroll
            for (int nf = 0; nf < 4; ++nf) {
                int n = wn * 64 + nf * 16 + (lane & 15);
                int slot = (kf * 4 + (lane >> 4)) ^ (n & 7);
                bf16x8s bh = *(const bf16x8s*)((const char*)Bs[0] + n * 128 + slot * 16);
                bf16x8s bl = *(const bf16x8s*)((const char*)Bs[1] + n * 128 + slot * 16);
#pragma unroll
                for (int mf = 0; mf < 4; ++mf) {
                    acc[mf][nf] = __builtin_amdgcn_mfma_f32_16x16x32_bf16(a[mf], bh, acc[mf][nf], 0, 0, 0);
                    acc[mf][nf] = __builtin_amdgcn_mfma_f32_16x16x32_bf16(a[mf], bl, acc[mf][nf], 0, 0, 0);
                }
            }
        }
        __syncthreads();
    }
#pragma unroll
    for (int mf = 0; mf < 4; ++mf) {
#pragma unroll
        for (int nf = 0; nf < 4; ++nf) {
            int col = n0 + wn * 64 + nf * 16 + (lane & 15);
#pragma unroll
            for (int r = 0; r < 4; ++r) {
                int lrow = wm * 64 + mf * 16 + (lane >> 4) * 4 + r;
                int pos = row0 + lrow;
                if (pos < cnt) {
                    atomicAdd(&out[(size_t)toks[lrow] * DIM + col], acc[mf][nf][r] * cws[lrow]);
                }
            }
        }
    }
}

// =====================================================================
// fp32 fallback GEMMs (verified baseline, used only if ws too small)
// =====================================================================
__global__ __launch_bounds__(256) void gemm1_kernel(
    const float* __restrict__ x,
    const float* __restrict__ wg_all, const float* __restrict__ wu_all,
    const int* __restrict__ counts, const int* __restrict__ elist,
    float* __restrict__ hbuf, int e)
{
    const int cnt = counts[e];
    const int row0 = blockIdx.x * 64;
    if (row0 >= cnt) return;
    const int col0 = blockIdx.y * 64;
    __shared__ float Ast[16][68];
    __shared__ float Bg[16][64];
    __shared__ float Bu[16][64];
    __shared__ int rows[64];
    const int tid = threadIdx.x;
    if (tid < 64) {
        int pos = row0 + tid;
        rows[tid] = (pos < cnt) ? elist[e * T_TOK + pos] : 0;
    }
    __syncthreads();
    const float* wg = wg_all + (size_t)e * DIM * HID;
    const float* wu = wu_all + (size_t)e * DIM * HID;
    const int tx = tid & 15, ty = tid >> 4;
    const int ar = tid >> 2, ac = (tid & 3) * 4;
    const int br = tid >> 4, bc = (tid & 15) * 4;
    const int myrow = rows[ar];
    float ag[4][4] = {{0.f}}, au[4][4] = {{0.f}};
    for (int k0 = 0; k0 < DIM; k0 += 16) {
        const float4 av = *(const float4*)(x + (size_t)myrow * DIM + k0 + ac);
        const float4 bgv = *(const float4*)(wg + (size_t)(k0 + br) * HID + col0 + bc);
        const float4 buv = *(const float4*)(wu + (size_t)(k0 + br) * HID + col0 + bc);
        Ast[ac + 0][ar] = av.x; Ast[ac + 1][ar] = av.y;
        Ast[ac + 2][ar] = av.z; Ast[ac + 3][ar] = av.w;
        *(float4*)&Bg[br][bc] = bgv;
        *(float4*)&Bu[br][bc] = buv;
        __syncthreads();
#pragma unroll
        for (int kk = 0; kk < 16; ++kk) {
            const float4 a4 = *(const float4*)&Ast[kk][ty * 4];
            const float4 bg4 = *(const float4*)&Bg[kk][tx * 4];
            const float4 bu4 = *(const float4*)&Bu[kk][tx * 4];
            const float a[4] = {a4.x, a4.y, a4.z, a4.w};
            const float bgj[4] = {bg4.x, bg4.y, bg4.z, bg4.w};
            const float buj[4] = {bu4.x, bu4.y, bu4.z, bu4.w};
#pragma unroll
            for (int i = 0; i < 4; ++i)
#pragma unroll
                for (int j = 0; j < 4; ++j) {
                    ag[i][j] += a[i] * bgj[j];
                    au[i][j] += a[i] * buj[j];
                }
        }
        __syncthreads();
    }
#pragma unroll
    for (int i = 0; i < 4; ++i) {
        const int pos = row0 + ty * 4 + i;
        if (pos < cnt) {
            float4 hv;
#pragma unroll
            for (int j = 0; j < 4; ++j) {
                const float g = ag[i][j];
                const float u = au[i][j];
                (&hv.x)[j] = (g / (1.0f + expf(-g))) * u;
            }
            *(float4*)(hbuf + (size_t)pos * HID + col0 + tx * 4) = hv;
        }
    }
}

__global__ __launch_bounds__(256) void gemm2_kernel(
    const float* __restrict__ hbuf, const float* __restrict__ wd_all,
    const int* __restrict__ counts, const int* __restrict__ elist,
    const float* __restrict__ cw, float* __restrict__ out, int e)
{
    const int cnt = counts[e];
    const int row0 = blockIdx.x * 64;
    if (row0 >= cnt) return;
    const int col0 = blockIdx.y * 64;
    __shared__ float Ast[16][68];
    __shared__ float Bs[16][64];
    __shared__ int rows[64];
    __shared__ float cws[64];
    const int tid = threadIdx.x;
    if (tid < 64) {
        int pos = row0 + tid;
        const bool v = pos < cnt;
        rows[tid] = v ? elist[e * T_TOK + pos] : 0;
        cws[tid] = v ? cw[e * T_TOK + pos] : 0.0f;
    }
    __syncthreads();
    const float* wd = wd_all + (size_t)e * HID * DIM;
    const int tx = tid & 15, ty = tid >> 4;
    const int ar = tid >> 2, ac = (tid & 3) * 4;
    const int br = tid >> 4, bc = (tid & 15) * 4;
    float acc[4][4] = {{0.f}};
    for (int k0 = 0; k0 < HID; k0 += 16) {
        const float4 av = *(const float4*)(hbuf + (size_t)(row0 + ar) * HID + k0 + ac);
        const float4 bv = *(const float4*)(wd + (size_t)(k0 + br) * DIM + col0 + bc);
        Ast[ac + 0][ar] = av.x; Ast[ac + 1][ar] = av.y;
        Ast[ac + 2][ar] = av.z; Ast[ac + 3][ar] = av.w;
        *(float4*)&Bs[br][bc] = bv;
        __syncthreads();
#pragma unroll
        for (int kk = 0; kk < 16; ++kk) {
            const float4 a4 = *(const float4*)&Ast[kk][ty * 4];
            const float4 b4 = *(const float4*)&Bs[kk][tx * 4];
            const float a[4] = {a4.x, a4.y, a4.z, a4.w};
            const float b[4] = {b4.x, b4.y, b4.z, b4.w};
#pragma unroll
            for (int i = 0; i < 4; ++i)
#pragma unroll
                for (int j = 0; j < 4; ++j)
                    acc[i][j] += a[i] * b[j];
        }
        __syncthreads();
    }
#pragma unroll
    for (int i = 0; i < 4; ++i) {
        const int pos = row0 + ty * 4 + i;
        if (pos < cnt) {
            const int t = rows[ty * 4 + i];
            const float w = cws[ty * 4 + i];
            float* op = out + (size_t)t * DIM + col0 + tx * 4;
            float4 o = *(float4*)op;
            o.x += w * acc[i][0]; o.y += w * acc[i][1];
            o.z += w * acc[i][2]; o.w += w * acc[i][3];
            *(float4*)op = o;
        }
    }
}

// =====================================================================
extern "C" void kernel_launch(void* const* d_in, const int* in_sizes, int n_in,
                              void* d_out, int out_size, void* d_ws, size_t ws_size,
                              hipStream_t stream)
{
    const float* x     = (const float*)d_in[0];
    const float* gw    = (const float*)d_in[1];
    const float* wgate = (const float*)d_in[2];
    const float* wup   = (const float*)d_in[3];
    const float* wdown = (const float*)d_in[4];
    float* out = (float*)d_out;

    char* ws = (char*)d_ws;
    int*   counts  = (int*)(ws);
    float* meanacc = (float*)(ws + 32);
    int*   elist   = (int*)(ws + WS_ELIST_OFF);
    float* cwp     = (float*)(ws + WS_CW_OFF);

    const size_t PLANE    = (size_t)NE * DIM * HID * 2;           // 64 MiB
    const size_t OFF_XBF  = (size_t)1 << 20;
    const size_t OFF_W    = OFF_XBF + (size_t)T_TOK * DIM * 2;
    const size_t OFF_HBUF = OFF_W + 4 * PLANE;                    // wd aliases wg
    const size_t NEED     = OFF_HBUF + (size_t)(2 * T_TOK + 128) * HID * 2;  // ~408 MB

    hipMemsetAsync(ws, 0, 1024, stream);
    hipMemsetAsync(d_out, 0, (size_t)out_size * sizeof(float), stream);

    gate_kernel<<<T_TOK / 4, 256, 0, stream>>>(x, gw, counts, meanacc, elist, cwp);
    finalize_kernel<<<1, 64, 0, stream>>>(meanacc, out);

    if (ws_size >= NEED) {
        u16* xbf  = (u16*)(ws + OFF_XBF);
        u16* wghi = (u16*)(ws + OFF_W + 0 * PLANE);
        u16* wglo = (u16*)(ws + OFF_W + 1 * PLANE);
        u16* wuhi = (u16*)(ws + OFF_W + 2 * PLANE);
        u16* wulo = (u16*)(ws + OFF_W + 3 * PLANE);
        u16* wdhi = wghi;   // aliased: converted after gemm1 (wg dead by then)
        u16* wdlo = wglo;
        u16* hb   = (u16*)(ws + OFF_HBUF);

        convert_x<<<(T_TOK * DIM / 4 + 255) / 256, 256, 0, stream>>>(x, xbf, T_TOK * DIM / 4);
        convert_wt<<<dim3(HID / 64, DIM / 64, NE), 256, 0, stream>>>(wgate, wghi, wglo, DIM, HID);
        convert_wt<<<dim3(HID / 64, DIM / 64, NE), 256, 0, stream>>>(wup,   wuhi, wulo, DIM, HID);

        gemm1_mfma<<<dim3(T_TOK / G1_BM, HID / G1_BN, NE), 256, 0, stream>>>(
            xbf, wghi, wglo, wuhi, wulo, counts, elist, hb);

        convert_wt<<<dim3(DIM / 64, HID / 64, NE), 256, 0, stream>>>(wdown, wdhi, wdlo, HID, DIM);

        gemm2_mfma<<<dim3(T_TOK / G2_BM, DIM / G2_BN, NE), 256, 0, stream>>>(
            hb, wdhi, wdlo, counts, elist, cwp, out);
    } else {
        float* hbuf = (float*)(ws + WS_HBUF_OFF);
        for (int e = 0; e < NE; ++e) {
            gemm1_kernel<<<dim3(T_TOK / 64, HID / 64), 256, 0, stream>>>(
                x, wgate, wup, counts, elist, hbuf, e);
            gemm2_kernel<<<dim3(T_TOK / 64, DIM / 64), 256, 0, stream>>>(
                hbuf, wdown, counts, elist, cwp, out, e);
        }
    }
}